// Round 4
// baseline (403.136 us; speedup 1.0000x reference)
//
#include <hip/hip_runtime.h>
#include <hip/hip_fp16.h>

#define IN_CH 16
#define OUT_CH 8

#define NT 256          // threads per block
#define EPT 16          // edges per thread in k_bin
#define TILE (NT*EPT)   // 4096 edges per tile
#define NBUK 512        // allocated buckets (489 active for N=500k)
#define BSHIFT 10       // bucket = dst >> 10  (1024 nodes per bucket)
#define BNODES 1024
#define BMASK 1023
#define SRCBITS 19      // src < 2^19 (N=500000 < 524288)
#define SRCMASK 0x7FFFF
#define CAP 12288       // slots per bucket (mean 10240, +20 sigma)
#define NSEG 2          // edge-list segments per bucket in k_accum

// ---- K1: tile-local counting sort of edges into coarse dst-buckets ----
__global__ void __launch_bounds__(NT) k_bin(const int* __restrict__ src,
                                            const int* __restrict__ dst, int E,
                                            int* __restrict__ gcur,
                                            unsigned* __restrict__ gbuf) {
    __shared__ int hist[NBUK];
    __shared__ int lofs[NBUK];
    __shared__ int gbase[NBUK];
    __shared__ int lcur[NBUK];
    __shared__ int scn[NT];
    __shared__ unsigned stage[TILE];
    __shared__ unsigned short posb[TILE];

    int t = threadIdx.x;
    long base = (long)blockIdx.x * TILE;
    int cnt = E - (int)base;
    if (cnt > TILE) cnt = TILE;

    for (int j = t; j < NBUK; j += NT) hist[j] = 0;
    __syncthreads();

    unsigned v[EPT];
    int bk[EPT];
#pragma unroll
    for (int k = 0; k < EPT; k++) {
        int idx = t + k * NT;
        if (idx < cnt) {
            int s = src[base + idx];
            int d = dst[base + idx];
            bk[k] = d >> BSHIFT;
            v[k] = ((unsigned)(d & BMASK) << SRCBITS) | (unsigned)s;
            atomicAdd(&hist[bk[k]], 1);
        } else {
            bk[k] = -1;
        }
    }
    __syncthreads();

    // block exclusive scan over 512 bucket counts (2 buckets per thread)
    int a0 = hist[2 * t], a1 = hist[2 * t + 1];
    int ts = a0 + a1;
    scn[t] = ts;
    __syncthreads();
    for (int d = 1; d < NT; d <<= 1) {
        int x = scn[t];
        int y = (t >= d) ? scn[t - d] : 0;
        __syncthreads();
        scn[t] = x + y;
        __syncthreads();
    }
    int excl = scn[t] - ts;
    lofs[2 * t] = excl;
    lofs[2 * t + 1] = excl + a0;
    lcur[2 * t] = excl;
    lcur[2 * t + 1] = excl + a0;
    // reserve global ranges (the only fabric atomics in the pipeline)
    if (a0 > 0) gbase[2 * t] = atomicAdd(&gcur[2 * t], a0);
    if (a1 > 0) gbase[2 * t + 1] = atomicAdd(&gcur[2 * t + 1], a1);
    __syncthreads();

    // place edges into LDS staging (tile-local counting sort)
#pragma unroll
    for (int k = 0; k < EPT; k++) {
        if (bk[k] >= 0) {
            int slot = atomicAdd(&lcur[bk[k]], 1);
            stage[slot] = v[k];
            posb[slot] = (unsigned short)bk[k];
        }
    }
    __syncthreads();

    // coalesced write-out of bucket runs
#pragma unroll
    for (int k = 0; k < EPT; k++) {
        int idx = t + k * NT;
        if (idx < cnt) {
            int b2 = posb[idx];
            int off = idx - lofs[b2] + gbase[b2];
            gbuf[(size_t)b2 * CAP + off] = stage[idx];
        }
    }
}

// ---- K2: per-bucket degree count (LDS atomics) -> dinv ----
__global__ void __launch_bounds__(NT) k_deg(const unsigned* __restrict__ gbuf,
                                            const int* __restrict__ gcur,
                                            float* __restrict__ dinv, int N) {
    __shared__ int ldeg[BNODES];
    int b = blockIdx.x, t = threadIdx.x;
    for (int j = t; j < BNODES; j += NT) ldeg[j] = 0;
    __syncthreads();

    int cnt = gcur[b];
    const unsigned* p = gbuf + (size_t)b * CAP;
    for (int i = t; i < cnt; i += NT) {
        unsigned val = p[i];
        atomicAdd(&ldeg[val >> SRCBITS], 1);
    }
    __syncthreads();

    int nb = b << BSHIFT;
    for (int j = t; j < BNODES; j += NT) {
        int n = nb + j;
        if (n < N) dinv[n] = rsqrtf(1.0f + (float)ldeg[j]);
    }
}

// ---- K3: hp16 = fp16( dinv * (x @ W^T) ), one 16 B row per node ----
__global__ void __launch_bounds__(NT) k_transform(const float* __restrict__ x,
                                                  const float* __restrict__ W,
                                                  const float* __restrict__ dinv,
                                                  uint4* __restrict__ hp16, int N) {
    __shared__ float Ws[OUT_CH * IN_CH];
    int t = threadIdx.x;
    if (t < OUT_CH * IN_CH) Ws[t] = W[t];
    __syncthreads();

    int n = blockIdx.x * blockDim.x + t;
    if (n >= N) return;

    const float4* xp = (const float4*)(x + (size_t)n * IN_CH);
    float4 a0 = xp[0], a1 = xp[1], a2 = xp[2], a3 = xp[3];
    float xi[IN_CH] = {a0.x, a0.y, a0.z, a0.w, a1.x, a1.y, a1.z, a1.w,
                       a2.x, a2.y, a2.z, a2.w, a3.x, a3.y, a3.z, a3.w};

    float di = dinv[n];

    float h[OUT_CH];
#pragma unroll
    for (int o = 0; o < OUT_CH; o++) {
        float s = 0.0f;
#pragma unroll
        for (int i = 0; i < IN_CH; i++) s += xi[i] * Ws[o * IN_CH + i];
        h[o] = s * di;
    }

    union { uint4 u; __half2 h2[4]; } pk;
    pk.h2[0] = __float22half2_rn(make_float2(h[0], h[1]));
    pk.h2[1] = __float22half2_rn(make_float2(h[2], h[3]));
    pk.h2[2] = __float22half2_rn(make_float2(h[4], h[5]));
    pk.h2[3] = __float22half2_rn(make_float2(h[6], h[7]));
    hp16[n] = pk.u;
}

// ---- K4: per-bucket-segment accumulate in LDS -> partial ----
// acc stride 9 floats/node: (dl*9+c) % 32 spreads over all banks (9 coprime 32)
__device__ __forceinline__ void accum_one(float* __restrict__ acc, unsigned v, uint4 g) {
    int dl = v >> SRCBITS;
    union { uint4 u; __half2 h2[4]; } pk;
    pk.u = g;
    float2 f0 = __half22float2(pk.h2[0]);
    float2 f1 = __half22float2(pk.h2[1]);
    float2 f2 = __half22float2(pk.h2[2]);
    float2 f3 = __half22float2(pk.h2[3]);
    float* A = &acc[dl * 9];
    atomicAdd(A + 0, f0.x); atomicAdd(A + 1, f0.y);
    atomicAdd(A + 2, f1.x); atomicAdd(A + 3, f1.y);
    atomicAdd(A + 4, f2.x); atomicAdd(A + 5, f2.y);
    atomicAdd(A + 6, f3.x); atomicAdd(A + 7, f3.y);
}

__global__ void __launch_bounds__(NT) k_accum(const unsigned* __restrict__ gbuf,
                                              const int* __restrict__ gcur,
                                              const uint4* __restrict__ hp16,
                                              float* __restrict__ partial) {
    __shared__ float acc[BNODES * 9];
    int b = blockIdx.x, s = blockIdx.y, t = threadIdx.x;
    for (int j = t; j < BNODES * 9; j += NT) acc[j] = 0.0f;
    __syncthreads();

    int cnt = gcur[b];
    int lo = (int)((long)cnt * s / NSEG);
    int hi = (int)((long)cnt * (s + 1) / NSEG);
    const unsigned* p = gbuf + (size_t)b * CAP;

    int i = lo + t;
    for (; i + 3 * NT < hi; i += 4 * NT) {
        unsigned v0 = p[i], v1 = p[i + NT], v2 = p[i + 2 * NT], v3 = p[i + 3 * NT];
        uint4 g0 = hp16[v0 & SRCMASK];
        uint4 g1 = hp16[v1 & SRCMASK];
        uint4 g2 = hp16[v2 & SRCMASK];
        uint4 g3 = hp16[v3 & SRCMASK];
        accum_one(acc, v0, g0);
        accum_one(acc, v1, g1);
        accum_one(acc, v2, g2);
        accum_one(acc, v3, g3);
    }
    for (; i < hi; i += NT) {
        unsigned v0 = p[i];
        uint4 g0 = hp16[v0 & SRCMASK];
        accum_one(acc, v0, g0);
    }
    __syncthreads();

    // coalesced dump of this segment's accumulator
    float* pp = partial + ((size_t)(b * NSEG + s) * BNODES) * OUT_CH;
    for (int j = t; j < BNODES; j += NT) {
        float4* dst4 = (float4*)(pp + j * OUT_CH);
        const float* A = &acc[j * 9];
        dst4[0] = make_float4(A[0], A[1], A[2], A[3]);
        dst4[1] = make_float4(A[4], A[5], A[6], A[7]);
    }
}

// ---- K5: merge segments + self-loop + scale + bias -> out ----
__global__ void __launch_bounds__(NT) k_merge(const float* __restrict__ partial,
                                              const uint4* __restrict__ hp16,
                                              const float* __restrict__ dinv,
                                              const float* __restrict__ bias,
                                              float* __restrict__ out, int N) {
    int n = blockIdx.x * blockDim.x + threadIdx.x;
    if (n >= N) return;
    int b = n >> BSHIFT, j = n & BMASK;

    const float4* p0 = (const float4*)(partial + ((size_t)(b * NSEG) * BNODES + j) * OUT_CH);
    const float4* p1 = (const float4*)(partial + ((size_t)(b * NSEG + 1) * BNODES + j) * OUT_CH);
    float4 a0 = p0[0], a1 = p0[1];
    float4 c0 = p1[0], c1 = p1[1];

    union { uint4 u; __half2 h2[4]; } pk;
    pk.u = hp16[n];
    float2 f0 = __half22float2(pk.h2[0]);
    float2 f1 = __half22float2(pk.h2[1]);
    float2 f2 = __half22float2(pk.h2[2]);
    float2 f3 = __half22float2(pk.h2[3]);

    float di = dinv[n];
    const float4* b4 = (const float4*)bias;
    float4 bb0 = b4[0], bb1 = b4[1];

    float4 o0, o1;
    o0.x = (a0.x + c0.x + f0.x) * di + bb0.x;
    o0.y = (a0.y + c0.y + f0.y) * di + bb0.y;
    o0.z = (a0.z + c0.z + f1.x) * di + bb0.z;
    o0.w = (a0.w + c0.w + f1.y) * di + bb0.w;
    o1.x = (a1.x + c1.x + f2.x) * di + bb1.x;
    o1.y = (a1.y + c1.y + f2.y) * di + bb1.y;
    o1.z = (a1.z + c1.z + f3.x) * di + bb1.z;
    o1.w = (a1.w + c1.w + f3.y) * di + bb1.w;

    float4* op = (float4*)(out + (size_t)n * OUT_CH);
    op[0] = o0;
    op[1] = o1;
}

extern "C" void kernel_launch(void* const* d_in, const int* in_sizes, int n_in,
                              void* d_out, int out_size, void* d_ws, size_t ws_size,
                              hipStream_t stream) {
    const float* x  = (const float*)d_in[0];
    const int*   ei = (const int*)d_in[1];   // [2, E] int32
    const float* W  = (const float*)d_in[2];
    const float* b  = (const float*)d_in[3];
    float* out = (float*)d_out;

    const int N = in_sizes[0] / IN_CH;
    const int E = in_sizes[1] / 2;
    const int* src = ei;
    const int* dst = ei + E;

    const int nbuckets = (N + BNODES - 1) >> BSHIFT;   // 489

    // workspace: gcur[NBUK] | dinv[N] | hp16[N] (16 B) | gbuf[NBUK*CAP] | partial[nbuk*NSEG*BNODES*8]
    int*      gcur = (int*)d_ws;
    float*    dinv = (float*)(gcur + NBUK);
    uint4*    hp16 = (uint4*)(dinv + N);
    unsigned* gbuf = (unsigned*)(hp16 + N);
    float*    partial = (float*)(gbuf + (size_t)NBUK * CAP);

    const int tiles = (E + TILE - 1) / TILE;           // 1221
    dim3 blkN((N + NT - 1) / NT);
    dim3 blkAcc(nbuckets, NSEG);

    hipMemsetAsync(gcur, 0, NBUK * sizeof(int), stream);
    k_bin<<<tiles, NT, 0, stream>>>(src, dst, E, gcur, gbuf);
    k_deg<<<nbuckets, NT, 0, stream>>>(gbuf, gcur, dinv, N);
    k_transform<<<blkN, NT, 0, stream>>>(x, W, dinv, hp16, N);
    k_accum<<<blkAcc, NT, 0, stream>>>(gbuf, gcur, hp16, partial);
    k_merge<<<blkN, NT, 0, stream>>>(partial, hp16, dinv, b, out, N);
}

// Round 5
// 255.869 us; speedup vs baseline: 1.5756x; 1.5756x over previous
//
#include <hip/hip_runtime.h>
#include <hip/hip_fp16.h>

#define IN_CH 16
#define OUT_CH 8

#define NT 256          // threads per block
#define EPT 16          // edges per thread in k_bin
#define TILE (NT*EPT)   // 4096 edges per tile
#define NBUK 512        // allocated buckets (489 active for N=500k)
#define BSHIFT 10       // bucket = dst >> 10  (1024 nodes per bucket)
#define BNODES 1024
#define BMASK 1023
#define SRCBITS 19      // src < 2^19 (N=500000 < 524288)
#define SRCMASK 0x7FFFF
#define CAP 12288       // slots per bucket (mean 10240, +20 sigma)

// ---- K1: tile-local counting sort of edges into coarse dst-buckets ----
__global__ void __launch_bounds__(NT) k_bin(const int* __restrict__ src,
                                            const int* __restrict__ dst, int E,
                                            int* __restrict__ gcur,
                                            unsigned* __restrict__ gbuf) {
    __shared__ int hist[NBUK];
    __shared__ int lofs[NBUK];
    __shared__ int gbase[NBUK];
    __shared__ int lcur[NBUK];
    __shared__ int scn[NT];
    __shared__ unsigned stage[TILE];
    __shared__ unsigned short posb[TILE];

    int t = threadIdx.x;
    long base = (long)blockIdx.x * TILE;
    int cnt = E - (int)base;
    if (cnt > TILE) cnt = TILE;

    for (int j = t; j < NBUK; j += NT) hist[j] = 0;
    __syncthreads();

    unsigned v[EPT];
    int bk[EPT];
#pragma unroll
    for (int k = 0; k < EPT; k++) {
        int idx = t + k * NT;
        if (idx < cnt) {
            int s = src[base + idx];
            int d = dst[base + idx];
            bk[k] = d >> BSHIFT;
            v[k] = ((unsigned)(d & BMASK) << SRCBITS) | (unsigned)s;
            atomicAdd(&hist[bk[k]], 1);
        } else {
            bk[k] = -1;
        }
    }
    __syncthreads();

    // block exclusive scan over 512 bucket counts (2 buckets per thread)
    int a0 = hist[2 * t], a1 = hist[2 * t + 1];
    int ts = a0 + a1;
    scn[t] = ts;
    __syncthreads();
    for (int d = 1; d < NT; d <<= 1) {
        int x = scn[t];
        int y = (t >= d) ? scn[t - d] : 0;
        __syncthreads();
        scn[t] = x + y;
        __syncthreads();
    }
    int excl = scn[t] - ts;
    lofs[2 * t] = excl;
    lofs[2 * t + 1] = excl + a0;
    lcur[2 * t] = excl;
    lcur[2 * t + 1] = excl + a0;
    if (a0 > 0) gbase[2 * t] = atomicAdd(&gcur[2 * t], a0);
    if (a1 > 0) gbase[2 * t + 1] = atomicAdd(&gcur[2 * t + 1], a1);
    __syncthreads();

    // place edges into LDS staging (tile-local counting sort)
#pragma unroll
    for (int k = 0; k < EPT; k++) {
        if (bk[k] >= 0) {
            int slot = atomicAdd(&lcur[bk[k]], 1);
            stage[slot] = v[k];
            posb[slot] = (unsigned short)bk[k];
        }
    }
    __syncthreads();

    // coalesced write-out of bucket runs
#pragma unroll
    for (int k = 0; k < EPT; k++) {
        int idx = t + k * NT;
        if (idx < cnt) {
            int b2 = posb[idx];
            int off = idx - lofs[b2] + gbase[b2];
            gbuf[(size_t)b2 * CAP + off] = stage[idx];
        }
    }
}

// ---- K2: per-bucket counting sort by local dst; emits sorted src array,
//          per-node offs/cnts, and dinv. Zero global atomics. ----
__global__ void __launch_bounds__(NT) k_sort(unsigned* __restrict__ gbuf,
                                             const int* __restrict__ gcur,
                                             float* __restrict__ dinv,
                                             int* __restrict__ offs,
                                             int* __restrict__ cnts, int N) {
    __shared__ unsigned sorted[CAP];   // 48 KB
    __shared__ int hist[BNODES];       // 4 KB
    __shared__ int cur[BNODES];        // 4 KB (start offsets, then bumped)
    __shared__ int scn[NT];            // 1 KB

    int b = blockIdx.x, t = threadIdx.x;
    int cnt = gcur[b];
    unsigned* p = gbuf + (size_t)b * CAP;

    for (int j = t; j < BNODES; j += NT) hist[j] = 0;
    __syncthreads();

    // pass 1: histogram of local dst
    for (int i = t; i < cnt; i += NT)
        atomicAdd(&hist[p[i] >> SRCBITS], 1);
    __syncthreads();

    // scan 1024 counts, 4 per thread
    int h0 = hist[4 * t], h1 = hist[4 * t + 1], h2 = hist[4 * t + 2], h3 = hist[4 * t + 3];
    int ts = h0 + h1 + h2 + h3;
    scn[t] = ts;
    __syncthreads();
    for (int d = 1; d < NT; d <<= 1) {
        int x = scn[t];
        int y = (t >= d) ? scn[t - d] : 0;
        __syncthreads();
        scn[t] = x + y;
        __syncthreads();
    }
    int e0 = scn[t] - ts;            // exclusive prefix
    int e1 = e0 + h0, e2 = e1 + h1, e3 = e2 + h2;
    cur[4 * t] = e0; cur[4 * t + 1] = e1; cur[4 * t + 2] = e2; cur[4 * t + 3] = e3;

    // emit offs / cnts / dinv (vectorized; 4 consecutive nodes per thread)
    int nb = b << BSHIFT;
    int n0 = nb + 4 * t;
    int gofs = b * CAP;
    if (n0 + 3 < N) {
        *(int4*)(offs + n0) = make_int4(gofs + e0, gofs + e1, gofs + e2, gofs + e3);
        *(int4*)(cnts + n0) = make_int4(h0, h1, h2, h3);
        *(float4*)(dinv + n0) = make_float4(rsqrtf(1.0f + (float)h0), rsqrtf(1.0f + (float)h1),
                                            rsqrtf(1.0f + (float)h2), rsqrtf(1.0f + (float)h3));
    } else {
#pragma unroll
        for (int k = 0; k < 4; k++) {
            int n = n0 + k;
            if (n < N) {
                int hk = (&h0)[0]; // avoid UB: select below
                int hv = (k == 0) ? h0 : (k == 1) ? h1 : (k == 2) ? h2 : h3;
                int ev = (k == 0) ? e0 : (k == 1) ? e1 : (k == 2) ? e2 : e3;
                (void)hk;
                offs[n] = gofs + ev;
                cnts[n] = hv;
                dinv[n] = rsqrtf(1.0f + (float)hv);
            }
        }
    }
    __syncthreads();

    // pass 2: scatter into LDS sorted[] (strip dl bits; keep src only)
    for (int i = t; i < cnt; i += NT) {
        unsigned v = p[i];
        int slot = atomicAdd(&cur[v >> SRCBITS], 1);
        sorted[slot] = v & SRCMASK;
    }
    __syncthreads();

    // pass 3: coalesced write-back
    for (int i = t; i < cnt; i += NT) p[i] = sorted[i];
}

// ---- K3: hp16 = fp16( dinv * (x @ W^T) ), one 16 B row per node ----
__global__ void __launch_bounds__(NT) k_transform(const float* __restrict__ x,
                                                  const float* __restrict__ W,
                                                  const float* __restrict__ dinv,
                                                  uint4* __restrict__ hp16, int N) {
    __shared__ float Ws[OUT_CH * IN_CH];
    int t = threadIdx.x;
    if (t < OUT_CH * IN_CH) Ws[t] = W[t];
    __syncthreads();

    int n = blockIdx.x * blockDim.x + t;
    if (n >= N) return;

    const float4* xp = (const float4*)(x + (size_t)n * IN_CH);
    float4 a0 = xp[0], a1 = xp[1], a2 = xp[2], a3 = xp[3];
    float xi[IN_CH] = {a0.x, a0.y, a0.z, a0.w, a1.x, a1.y, a1.z, a1.w,
                       a2.x, a2.y, a2.z, a2.w, a3.x, a3.y, a3.z, a3.w};

    float di = dinv[n];

    float h[OUT_CH];
#pragma unroll
    for (int o = 0; o < OUT_CH; o++) {
        float s = 0.0f;
#pragma unroll
        for (int i = 0; i < IN_CH; i++) s += xi[i] * Ws[o * IN_CH + i];
        h[o] = s * di;
    }

    union { uint4 u; __half2 h2[4]; } pk;
    pk.h2[0] = __float22half2_rn(make_float2(h[0], h[1]));
    pk.h2[1] = __float22half2_rn(make_float2(h[2], h[3]));
    pk.h2[2] = __float22half2_rn(make_float2(h[4], h[5]));
    pk.h2[3] = __float22half2_rn(make_float2(h[6], h[7]));
    hp16[n] = pk.u;
}

// ---- K4: pull gather — one thread per node, no LDS, no atomics ----
__device__ __forceinline__ void acc_add(float* a, uint4 g) {
    union { uint4 u; __half2 h2[4]; } pk;
    pk.u = g;
    float2 f0 = __half22float2(pk.h2[0]);
    float2 f1 = __half22float2(pk.h2[1]);
    float2 f2 = __half22float2(pk.h2[2]);
    float2 f3 = __half22float2(pk.h2[3]);
    a[0] += f0.x; a[1] += f0.y; a[2] += f1.x; a[3] += f1.y;
    a[4] += f2.x; a[5] += f2.y; a[6] += f3.x; a[7] += f3.y;
}

__global__ void __launch_bounds__(NT) k_gather(const unsigned* __restrict__ gbuf,
                                               const int* __restrict__ offs,
                                               const int* __restrict__ cnts,
                                               const uint4* __restrict__ hp16,
                                               const float* __restrict__ dinv,
                                               const float* __restrict__ bias,
                                               float* __restrict__ out, int N) {
    int n = blockIdx.x * blockDim.x + threadIdx.x;
    if (n >= N) return;

    int e = offs[n];
    int end = e + cnts[n];

    // self-loop term
    float a[OUT_CH];
    {
        union { uint4 u; __half2 h2[4]; } pk;
        pk.u = hp16[n];
        float2 f0 = __half22float2(pk.h2[0]);
        float2 f1 = __half22float2(pk.h2[1]);
        float2 f2 = __half22float2(pk.h2[2]);
        float2 f3 = __half22float2(pk.h2[3]);
        a[0] = f0.x; a[1] = f0.y; a[2] = f1.x; a[3] = f1.y;
        a[4] = f2.x; a[5] = f2.y; a[6] = f3.x; a[7] = f3.y;
    }

    // 4-deep software pipeline of gathers
    for (; e + 3 < end; e += 4) {
        unsigned s0 = gbuf[e], s1 = gbuf[e + 1], s2 = gbuf[e + 2], s3 = gbuf[e + 3];
        uint4 g0 = hp16[s0];
        uint4 g1 = hp16[s1];
        uint4 g2 = hp16[s2];
        uint4 g3 = hp16[s3];
        acc_add(a, g0); acc_add(a, g1); acc_add(a, g2); acc_add(a, g3);
    }
    for (; e < end; e++) {
        uint4 g0 = hp16[gbuf[e]];
        acc_add(a, g0);
    }

    float di = dinv[n];
    const float4* b4 = (const float4*)bias;
    float4 bb0 = b4[0], bb1 = b4[1];
    float4 o0, o1;
    o0.x = a[0] * di + bb0.x; o0.y = a[1] * di + bb0.y;
    o0.z = a[2] * di + bb0.z; o0.w = a[3] * di + bb0.w;
    o1.x = a[4] * di + bb1.x; o1.y = a[5] * di + bb1.y;
    o1.z = a[6] * di + bb1.z; o1.w = a[7] * di + bb1.w;

    float4* op = (float4*)(out + (size_t)n * OUT_CH);
    op[0] = o0;
    op[1] = o1;
}

extern "C" void kernel_launch(void* const* d_in, const int* in_sizes, int n_in,
                              void* d_out, int out_size, void* d_ws, size_t ws_size,
                              hipStream_t stream) {
    const float* x  = (const float*)d_in[0];
    const int*   ei = (const int*)d_in[1];   // [2, E] int32
    const float* W  = (const float*)d_in[2];
    const float* b  = (const float*)d_in[3];
    float* out = (float*)d_out;

    const int N = in_sizes[0] / IN_CH;
    const int E = in_sizes[1] / 2;
    const int* src = ei;
    const int* dst = ei + E;

    const int nbuckets = (N + BNODES - 1) >> BSHIFT;   // 489

    // workspace: gcur[NBUK] | dinv[N] | hp16[N]16B | gbuf[NBUK*CAP] | offs[N] | cnts[N]  (~39 MB)
    int*      gcur = (int*)d_ws;
    float*    dinv = (float*)(gcur + NBUK);
    uint4*    hp16 = (uint4*)(dinv + N);
    unsigned* gbuf = (unsigned*)(hp16 + N);
    int*      offs = (int*)(gbuf + (size_t)NBUK * CAP);
    int*      cnts = offs + N;

    const int tiles = (E + TILE - 1) / TILE;           // 1221
    dim3 blkN((N + NT - 1) / NT);

    hipMemsetAsync(gcur, 0, NBUK * sizeof(int), stream);
    k_bin<<<tiles, NT, 0, stream>>>(src, dst, E, gcur, gbuf);
    k_sort<<<nbuckets, NT, 0, stream>>>(gbuf, gcur, dinv, offs, cnts, N);
    k_transform<<<blkN, NT, 0, stream>>>(x, W, dinv, hp16, N);
    k_gather<<<blkN, NT, 0, stream>>>(gbuf, offs, cnts, hp16, dinv, b, out, N);
}